// Round 8
// baseline (493.191 us; speedup 1.0000x reference)
//
#include <hip/hip_runtime.h>
#include <math.h>

// Problem constants (from reference): B=32, C=D=64, H=W=64, K=1024
constexpr int K_CODES = 1024;
constexpr int D_DIM   = 64;
constexpr int HW      = 64 * 64;          // 4096
constexpr int NPOS    = 32 * HW;          // 131072 positions
constexpr int CHW     = D_DIM * HW;       // 262144 (per-batch stride)

// Split-K structure: 64 positions/block, 4 k-split waves (256 codes each).
// Chunked codebook staging: 16 chunks x (16 codes per quarter x 4) = 64 codes.
constexpr int KSPLIT  = 4;
constexpr int KRANGE  = K_CODES / KSPLIT;   // 256
constexpr int NCHUNK  = 16;
constexpr int CJ      = KRANGE / NCHUNK;    // 16 codes per quarter per chunk

typedef float f32x16 __attribute__((ext_vector_type(16)));

#define REPEAT16(M) M(0) M(1) M(2) M(3) M(4) M(5) M(6) M(7) \
                    M(8) M(9) M(10) M(11) M(12) M(13) M(14) M(15)

// ws layout (floats): [0..1023] c2 (codebook squared norms), [1024..2047] histogram
__global__ void vq_prep(const float* __restrict__ cb, float* __restrict__ ws) {
    int k = blockIdx.x * blockDim.x + threadIdx.x;
    if (k < K_CODES) {
        const float4* row = reinterpret_cast<const float4*>(cb + k * D_DIM);
        float s0 = 0.f, s1 = 0.f, s2 = 0.f, s3 = 0.f;
#pragma unroll
        for (int i = 0; i < 16; ++i) {
            float4 v = row[i];
            s0 = fmaf(v.x, v.x, s0);
            s1 = fmaf(v.y, v.y, s1);
            s2 = fmaf(v.z, v.z, s2);
            s3 = fmaf(v.w, v.w, s3);
        }
        ws[k] = (s0 + s1) + (s2 + s3);
        ws[K_CODES + k] = 0.0f;
    }
}

// r7 evidence: VALUBusy 74% but dur flat -> per-iter global c2 load exposed
// + only 2 waves/SIMD to hide anything. This version: 4x waves via split-K
// (grid 2048 blocks), ALL inner-loop memory in LDS (c2 staged once, codebook
// chunks double-buffered through registers: loads issued BEFORE compute).
// Numerics: identical FMA orderings; cross-quarter combine via u64
// (dist,idx) min == global first-index argmin. Bit-exact vs rounds 1-7.
__global__ __launch_bounds__(256)
__attribute__((amdgpu_waves_per_eu(1, 3)))
void vq_main(
    const float* __restrict__ in, const float* __restrict__ cb,
    float* __restrict__ out, float* __restrict__ ws) {
    float* hist = ws + K_CODES;

    __shared__ float4 cbs[KSPLIT * CJ * 16];            // 64 codes x 64f = 16 KB
    __shared__ float  c2s[K_CODES];                     // 4 KB
    __shared__ unsigned long long comb[64][KSPLIT];     // 2 KB

    const int t   = threadIdx.x;
    const int pos = t & 63;          // position within block
    const int q   = t >> 6;          // k-split (wave id)
    const int n   = blockIdx.x * 64 + pos;
    const int b   = n >> 12;         // / 4096
    const int hw  = n & 4095;
    const float* xb = in + (size_t)b * CHW + hw;

    // stage c2 once (1024 floats / 256 threads)
#pragma unroll
    for (int j = 0; j < 4; ++j) c2s[t + j * 256] = ws[t + j * 256];

    // load x into SSA ext-vectors (compile-time subscripts only)
    f32x16 va, vb, vc, vd;
#define LDI(i) \
    va[i] = xb[(size_t)(4 * i + 0) * HW]; \
    vb[i] = xb[(size_t)(4 * i + 1) * HW]; \
    vc[i] = xb[(size_t)(4 * i + 2) * HW]; \
    vd[i] = xb[(size_t)(4 * i + 3) * HW];
    REPEAT16(LDI)
#undef LDI

    float s0 = 0.f, s1 = 0.f, s2 = 0.f, s3 = 0.f;
#define SQI(i) \
    s0 = fmaf(va[i], va[i], s0); \
    s1 = fmaf(vb[i], vb[i], s1); \
    s2 = fmaf(vc[i], vc[i], s2); \
    s3 = fmaf(vd[i], vd[i], s3);
    REPEAT16(SQI)
#undef SQI
    const float x2 = (s0 + s1) + (s2 + s3);

    // chunk staging: flat element e in [0,1024) -> quarter e>>8, local e&255;
    // src float4 idx = (e>>8)*4096 + ch*256 + (e&255)  (4 coalesced 4KB spans)
    const float4* cbv = reinterpret_cast<const float4*>(cb);
    float4* cbs_f = cbs;
#define SRC(e, ch) cbv[((e) >> 8) * (KRANGE * 16) + (ch) * 256 + ((e) & 255)]

    // prologue: stage chunk 0
    {
        float4 t0 = SRC(t, 0), t1 = SRC(t + 256, 0),
               t2 = SRC(t + 512, 0), t3 = SRC(t + 768, 0);
        cbs_f[t] = t0; cbs_f[t + 256] = t1;
        cbs_f[t + 512] = t2; cbs_f[t + 768] = t3;
    }
    __syncthreads();

    float best = INFINITY;
    int   bidx = 0;
    const float4* mybase = &cbs[q * CJ * 16];   // this wave's 16 codes

    for (int ch = 0; ch < NCHUNK; ++ch) {
        // issue next chunk's loads BEFORE compute (latency hides under FMA)
        float4 p0, p1, p2, p3;
        if (ch + 1 < NCHUNK) {
            p0 = SRC(t, ch + 1); p1 = SRC(t + 256, ch + 1);
            p2 = SRC(t + 512, ch + 1); p3 = SRC(t + 768, ch + 1);
        }

        for (int j = 0; j < CJ; ++j) {
            const int k = q * KRANGE + ch * CJ + j;
            const float4* crow = mybase + j * 16;   // wave-uniform -> broadcast
            float d0 = 0.f, d1 = 0.f, d2 = 0.f, d3 = 0.f;
#define DOTI(i) { \
            float4 v = crow[i]; \
            d0 = fmaf(va[i], v.x, d0); \
            d1 = fmaf(vb[i], v.y, d1); \
            d2 = fmaf(vc[i], v.z, d2); \
            d3 = fmaf(vd[i], v.w, d3); }
            REPEAT16(DOTI)
#undef DOTI
            float dot  = (d0 + d1) + (d2 + d3);
            float dist = (x2 - 2.0f * dot) + c2s[k];
            bool m = dist < best;       // strict < : first index on ties
            best = m ? dist : best;
            bidx = m ? k : bidx;
        }

        __syncthreads();                 // chunk fully consumed
        if (ch + 1 < NCHUNK) {
            cbs_f[t] = p0; cbs_f[t + 256] = p1;
            cbs_f[t + 512] = p2; cbs_f[t + 768] = p3;
        }
        __syncthreads();                 // next chunk visible
    }
#undef SRC

    // combine 4 quarters: u64 (monotone-dist, idx) min == global first-min
    unsigned db = __float_as_uint(best);
    db = (db & 0x80000000u) ? ~db : (db | 0x80000000u);
    comb[pos][q] = ((unsigned long long)db << 32) | (unsigned)bidx;
    __syncthreads();
    unsigned long long m0 = comb[pos][0];
    unsigned long long m1 = comb[pos][1];
    unsigned long long m2 = comb[pos][2];
    unsigned long long m3 = comb[pos][3];
    unsigned long long mm = m0 < m1 ? m0 : m1;
    mm = m2 < mm ? m2 : mm;
    mm = m3 < mm ? m3 : mm;
    const int fidx = (int)(mm & 0xffffffffu);

    // epilogue: wave q writes channels [16q,16q+16); uniform branch, coalesced
    float* ob = out + (size_t)b * CHW + hw;
    const float* __restrict__ qr = cb + fidx * D_DIM;
#define STI(i) { \
    float q0 = qr[4 * i + 0], q1 = qr[4 * i + 1], q2 = qr[4 * i + 2], q3 = qr[4 * i + 3]; \
    ob[(size_t)(4 * i + 0) * HW] = va[i] + (q0 - va[i]); \
    ob[(size_t)(4 * i + 1) * HW] = vb[i] + (q1 - vb[i]); \
    ob[(size_t)(4 * i + 2) * HW] = vc[i] + (q2 - vc[i]); \
    ob[(size_t)(4 * i + 3) * HW] = vd[i] + (q3 - vd[i]); }
    if (q == 0) {
        STI(0) STI(1) STI(2) STI(3)
        atomicAdd(&hist[fidx], 1.0f);
    } else if (q == 1) {
        STI(4) STI(5) STI(6) STI(7)
    } else if (q == 2) {
        STI(8) STI(9) STI(10) STI(11)
    } else {
        STI(12) STI(13) STI(14) STI(15)
    }
#undef STI
}

// perplexity: one block, 1024 threads (16 waves)
__global__ void vq_ppl(const float* __restrict__ ws, float* __restrict__ outp) {
    __shared__ float red[16];
    int t = threadIdx.x;
    float e = ws[K_CODES + t] * (1.0f / (float)NPOS);
    float term = e * logf(e + 1e-10f);
#pragma unroll
    for (int off = 32; off > 0; off >>= 1)
        term += __shfl_down(term, off, 64);
    int lane = t & 63, wid = t >> 6;
    if (lane == 0) red[wid] = term;
    __syncthreads();
    if (t == 0) {
        float s = 0.f;
#pragma unroll
        for (int i = 0; i < 16; ++i) s += red[i];
        *outp = expf(-s);
    }
}

extern "C" void kernel_launch(void* const* d_in, const int* in_sizes, int n_in,
                              void* d_out, int out_size, void* d_ws, size_t ws_size,
                              hipStream_t stream) {
    const float* in = (const float*)d_in[0];   // [32,64,64,64] fp32
    const float* cb = (const float*)d_in[1];   // [1024,64] fp32
    float* out = (float*)d_out;                // quantized [8388608] + ppl [1]
    float* ws  = (float*)d_ws;

    vq_prep<<<4, 256, 0, stream>>>(cb, ws);
    vq_main<<<NPOS / 64, 256, 0, stream>>>(in, cb, out, ws);
    vq_ppl<<<1, 1024, 0, stream>>>(ws, out + (size_t)8388608);
}

// Round 9
// 492.899 us; speedup vs baseline: 1.0006x; 1.0006x over previous
//
#include <hip/hip_runtime.h>
#include <math.h>

// B=32, C=D=64, H=W=64, K=1024
constexpr int K_CODES = 1024;
constexpr int D_DIM   = 64;
constexpr int HW      = 4096;
constexpr int NPOS    = 131072;
constexpr int CHW     = 262144;
constexpr int NTILE   = K_CODES / 16;   // 64 N-tiles of 16 codes

typedef short bf16x8 __attribute__((ext_vector_type(8)));
typedef float f32x4  __attribute__((ext_vector_type(4)));

__device__ __forceinline__ unsigned short f2bf(float f) {
    // round-to-nearest-even bf16 (finite inputs)
    unsigned u = __float_as_uint(f);
    return (unsigned short)((u + 0x7FFFu + ((u >> 16) & 1u)) >> 16);
}
__device__ __forceinline__ unsigned mapf(float f) {
    unsigned u = __float_as_uint(f);
    return (u & 0x80000000u) ? ~u : (u | 0x80000000u);
}
__device__ __forceinline__ float unmapf(unsigned v) {
    unsigned u = (v & 0x80000000u) ? (v & 0x7FFFFFFFu) : ~v;
    return __uint_as_float(u);
}

// ws layout: [0..1023] c2 fp32 | [1024..2047] histogram fp32 |
//            byte 8192.. : codebook bf16 [1024][64] (128 KB)
__global__ void vq_prep(const float* __restrict__ cb, float* __restrict__ ws) {
    int k = blockIdx.x * blockDim.x + threadIdx.x;
    if (k < K_CODES) {
        const float4* row = reinterpret_cast<const float4*>(cb + k * D_DIM);
        float s0 = 0.f, s1 = 0.f, s2 = 0.f, s3 = 0.f;
#pragma unroll
        for (int i = 0; i < 16; ++i) {
            float4 v = row[i];
            s0 = fmaf(v.x, v.x, s0);
            s1 = fmaf(v.y, v.y, s1);
            s2 = fmaf(v.z, v.z, s2);
            s3 = fmaf(v.w, v.w, s3);
        }
        ws[k] = (s0 + s1) + (s2 + s3);
        ws[K_CODES + k] = 0.0f;
        // bf16 codebook for the MFMA filter
        unsigned short* cbh = (unsigned short*)(ws + 2048);
#pragma unroll
        for (int d = 0; d < D_DIM; ++d) cbh[k * D_DIM + d] = f2bf(cb[k * D_DIM + d]);
    }
}

// Block = 256 thr (4 waves), 64 positions. Phase A: bf16 MFMA approx dists ->
// per-pos min. Phase B: re-run tiles; for candidates (approx dist within a
// sound error bound of the min) recompute EXACT fp32 dist in the r1-r8
// bit-exact order and take (dist,idx) u64-min == np first-index argmin.
__global__ __launch_bounds__(256)
__attribute__((amdgpu_waves_per_eu(1, 4)))
void vq_main(const float* __restrict__ in, const float* __restrict__ cb,
             float* __restrict__ out, float* __restrict__ ws) {
    float* hist = ws + K_CODES;
    const unsigned short* cbh = (const unsigned short*)(ws + 2048);

    __shared__ float x_lds[64][68];          // +4 pad: 16B-aligned rows
    __shared__ float x2_lds[64];
    __shared__ float c2s[K_CODES];
    __shared__ unsigned msl[64];
    __shared__ unsigned long long win[64];

    const int t   = threadIdx.x;
    const int l   = t & 63;
    const int w   = t >> 6;
    const int nbase = blockIdx.x * 64;       // 64 positions, same batch b
    const int b   = nbase >> 12;
    const int hw0 = nbase & 4095;
    const float* xb = in + (size_t)b * CHW + hw0;

    // stage x (coalesced: lanes -> consecutive hw), c2, init reducers
#pragma unroll
    for (int cc = 0; cc < 16; ++cc) {
        int c = w * 16 + cc;
        x_lds[l][c] = xb[(size_t)c * HW + l];
    }
#pragma unroll
    for (int j = 0; j < 4; ++j) c2s[t + j * 256] = ws[t + j * 256];
    if (t < 64) { msl[t] = 0xFFFFFFFFu; win[t] = ~0ull; }
    __syncthreads();

    // x2 in the exact 4-partial order (bit-identical to rounds 1-8)
    if (t < 64) {
        float s0 = 0.f, s1 = 0.f, s2 = 0.f, s3 = 0.f;
#pragma unroll
        for (int i = 0; i < 16; ++i) {
            s0 = fmaf(x_lds[t][4 * i + 0], x_lds[t][4 * i + 0], s0);
            s1 = fmaf(x_lds[t][4 * i + 1], x_lds[t][4 * i + 1], s1);
            s2 = fmaf(x_lds[t][4 * i + 2], x_lds[t][4 * i + 2], s2);
            s3 = fmaf(x_lds[t][4 * i + 3], x_lds[t][4 * i + 3], s3);
        }
        x2_lds[t] = (s0 + s1) + (s2 + s3);
    }
    __syncthreads();

    const int nlo = l & 15;   // A-row / B-col / D-col
    const int kq  = l >> 4;   // k-quarter

    // A fragments (this wave's 16 positions): A[m=nlo][k=kq*8+j (+32)]
    bf16x8 a0, a1;
#pragma unroll
    for (int j = 0; j < 8; ++j) {
        a0[j] = (short)f2bf(x_lds[w * 16 + nlo][kq * 8 + j]);
        a1[j] = (short)f2bf(x_lds[w * 16 + nlo][kq * 8 + 32 + j]);
    }
    // D rows this lane owns: pos = w*16 + kq*4 + r
    int   prow[4];
    float x2r[4];
#pragma unroll
    for (int r = 0; r < 4; ++r) { prow[r] = w * 16 + kq * 4 + r; x2r[r] = x2_lds[prow[r]]; }

    // ---- Phase A: approx distances, per-pos min ----
    for (int tile = 0; tile < NTILE; ++tile) {
        const unsigned short* bp = cbh + (tile * 16 + nlo) * D_DIM + kq * 8;
        bf16x8 b0 = *(const bf16x8*)(bp);
        bf16x8 b1 = *(const bf16x8*)(bp + 32);
        f32x4 acc = {0.f, 0.f, 0.f, 0.f};
        acc = __builtin_amdgcn_mfma_f32_16x16x32_bf16(a0, b0, acc, 0, 0, 0);
        acc = __builtin_amdgcn_mfma_f32_16x16x32_bf16(a1, b1, acc, 0, 0, 0);
        float c2n = c2s[tile * 16 + nlo];
#pragma unroll
        for (int r = 0; r < 4; ++r) {
            float dt = fmaf(-2.0f, acc[r], x2r[r]) + c2n;
            atomicMin(&msl[prow[r]], mapf(dt));
        }
    }
    __syncthreads();

    // candidate threshold: sound |approx-exact| bound with >=3x margin
    float thr[4];
#pragma unroll
    for (int r = 0; r < 4; ++r)
        thr[r] = unmapf(msl[prow[r]]) + (0.02f * sqrtf(x2r[r]) + 0.02f);

    // ---- Phase B: exact fp32 verify of candidates ----
    for (int tile = 0; tile < NTILE; ++tile) {
        const unsigned short* bp = cbh + (tile * 16 + nlo) * D_DIM + kq * 8;
        bf16x8 b0 = *(const bf16x8*)(bp);
        bf16x8 b1 = *(const bf16x8*)(bp + 32);
        f32x4 acc = {0.f, 0.f, 0.f, 0.f};
        acc = __builtin_amdgcn_mfma_f32_16x16x32_bf16(a0, b0, acc, 0, 0, 0);
        acc = __builtin_amdgcn_mfma_f32_16x16x32_bf16(a1, b1, acc, 0, 0, 0);
        float c2n = c2s[tile * 16 + nlo];
#pragma unroll
        for (int r = 0; r < 4; ++r) {
            float dt = fmaf(-2.0f, acc[r], x2r[r]) + c2n;
            if (dt <= thr[r]) {
                const int n = tile * 16 + nlo;
                const float4* cr = (const float4*)(cb + n * D_DIM);
                const float4* xr = (const float4*)(&x_lds[prow[r]][0]);
                float d0 = 0.f, d1 = 0.f, d2 = 0.f, d3 = 0.f;
#pragma unroll
                for (int i = 0; i < 16; ++i) {
                    float4 v = cr[i]; float4 xx = xr[i];
                    d0 = fmaf(xx.x, v.x, d0);
                    d1 = fmaf(xx.y, v.y, d1);
                    d2 = fmaf(xx.z, v.z, d2);
                    d3 = fmaf(xx.w, v.w, d3);
                }
                float dot  = (d0 + d1) + (d2 + d3);
                float dist = (x2r[r] - 2.0f * dot) + c2n;   // exact, same order
                unsigned long long pk =
                    ((unsigned long long)mapf(dist) << 32) | (unsigned)n;
                atomicMin(&win[prow[r]], pk);   // min dist, tie -> smallest idx
            }
        }
    }
    __syncthreads();

    // ---- finale: gather + straight-through output + histogram ----
    const int fidx = (int)(win[l] & 0xFFFFFFFFu);
    float* ob = out + (size_t)b * CHW + hw0;
    const float* qr = cb + fidx * D_DIM;
#pragma unroll
    for (int cc = 0; cc < 16; ++cc) {
        int c = w * 16 + cc;
        float x = x_lds[l][c];
        float q = qr[c];
        ob[(size_t)c * HW + l] = x + (q - x);
    }
    if (t < 64) atomicAdd(&hist[fidx], 1.0f);
}

// perplexity: one block, 1024 threads (16 waves)
__global__ void vq_ppl(const float* __restrict__ ws, float* __restrict__ outp) {
    __shared__ float red[16];
    int t = threadIdx.x;
    float e = ws[K_CODES + t] * (1.0f / (float)NPOS);
    float term = e * logf(e + 1e-10f);
#pragma unroll
    for (int off = 32; off > 0; off >>= 1)
        term += __shfl_down(term, off, 64);
    int lane = t & 63, wid = t >> 6;
    if (lane == 0) red[wid] = term;
    __syncthreads();
    if (t == 0) {
        float s = 0.f;
#pragma unroll
        for (int i = 0; i < 16; ++i) s += red[i];
        *outp = expf(-s);
    }
}

extern "C" void kernel_launch(void* const* d_in, const int* in_sizes, int n_in,
                              void* d_out, int out_size, void* d_ws, size_t ws_size,
                              hipStream_t stream) {
    const float* in = (const float*)d_in[0];   // [32,64,64,64] fp32
    const float* cb = (const float*)d_in[1];   // [1024,64] fp32
    float* out = (float*)d_out;                // quantized [8388608] + ppl [1]
    float* ws  = (float*)d_ws;                 // uses 8 KB + 128 KB bf16 codebook

    vq_prep<<<4, 256, 0, stream>>>(cb, ws);
    vq_main<<<NPOS / 64, 256, 0, stream>>>(in, cb, out, ws);
    vq_ppl<<<1, 1024, 0, stream>>>(ws, out + (size_t)8388608);
}